// Round 5
// baseline (198.046 us; speedup 1.0000x reference)
//
#include <hip/hip_runtime.h>
#include <hip/hip_bf16.h>
#include <stdint.h>

typedef __bf16 bf16x8 __attribute__((ext_vector_type(8)));
typedef __bf16 bf16x4 __attribute__((ext_vector_type(4)));
typedef float f32x4 __attribute__((ext_vector_type(4)));

#define DEV __device__ __forceinline__

DEV void gload_lds16(const void* g, void* l) {
  __builtin_amdgcn_global_load_lds((const __attribute__((address_space(1))) void*)g,
                                   (__attribute__((address_space(3))) void*)l, 16, 0, 0);
}

#define WAITV(n) asm volatile("s_waitcnt vmcnt(" #n ")" ::: "memory")
#define MFMA16x16(a, b, c) __builtin_amdgcn_mfma_f32_16x16x32_bf16(a, b, c, 0, 0, 0)

// ---------------- pack x: f32 -> bf16 ----------------
__global__ __launch_bounds__(256) void pack_x_kernel(const float* __restrict__ x,
                                                     __bf16* __restrict__ o, long n) {
  long i = ((long)blockIdx.x * 256 + threadIdx.x) * 4;
  const long stride = (long)gridDim.x * 256 * 4;
  for (; i < n; i += stride) {
    f32x4 v = *(const f32x4*)(x + i);
    bf16x4 b;
    b[0] = (__bf16)v[0]; b[1] = (__bf16)v[1]; b[2] = (__bf16)v[2]; b[3] = (__bf16)v[3];
    *(bf16x4*)(o + i) = b;
  }
}

// ---------------- pack W: [1024][1024] f32 -> Wt[e][d] bf16 (Wq scaled 1/32) ----------------
__global__ __launch_bounds__(256) void pack_w_kernel(const float* __restrict__ Wq,
                                                     const float* __restrict__ Wk,
                                                     const float* __restrict__ Wv,
                                                     __bf16* __restrict__ Wt) {
  const int w = blockIdx.z;
  const float* W = (w == 0) ? Wq : (w == 1) ? Wk : Wv;
  const float scale = (w == 0) ? 0.03125f : 1.0f;
  const int d0 = blockIdx.x * 64;
  const int e0 = blockIdx.y * 64;
  __shared__ __bf16 T[64][72];
  const int tid = threadIdx.x;
  const int r4 = tid >> 4;
  const int c4 = (tid & 15) * 4;
#pragma unroll
  for (int p = 0; p < 4; ++p) {
    int r = r4 + p * 16;
    f32x4 v = *(const f32x4*)(W + (long)(d0 + r) * 1024 + e0 + c4);
    T[r][c4 + 0] = (__bf16)(v[0] * scale);
    T[r][c4 + 1] = (__bf16)(v[1] * scale);
    T[r][c4 + 2] = (__bf16)(v[2] * scale);
    T[r][c4 + 3] = (__bf16)(v[3] * scale);
  }
  __syncthreads();
  const int e4 = tid >> 3;
  const int dd = (tid & 7) * 8;
#pragma unroll
  for (int p = 0; p < 2; ++p) {
    int e = e4 + p * 32;
    bf16x8 ov;
#pragma unroll
    for (int j = 0; j < 8; ++j) ov[j] = T[dd + j][e];
    *(bf16x8*)(Wt + (long)w * 1048576 + (long)(e0 + e) * 1024 + d0 + dd) = ov;
  }
}

// ---------------- pack bias: concat, bq scaled 1/32, stays f32 ----------------
__global__ __launch_bounds__(256) void pack_bias_kernel(const float* __restrict__ bq,
                                                        const float* __restrict__ bk,
                                                        const float* __restrict__ bv,
                                                        float* __restrict__ o) {
  int i = blockIdx.x * 256 + threadIdx.x;
  if (i < 1024) o[i] = bq[i] * 0.03125f;
  else if (i < 2048) o[i] = bk[i - 1024];
  else if (i < 3072) o[i] = bv[i - 2048];
}

// ---------------- GEMM: C[M,N] = A[M,K] * B[N,K]^T, 256x256 tile, wave 128x64 --------------
// BK=64, 8 waves (2M x 4N). LDS ring-2 (2 x 64 KiB). Per K-tile: 4 phases; ph0 reads all
// 8 B-frags (held whole tile) + A mi{0,1}; ph1..3 stream A mi-pairs. Stage gloads for t+1
// spread over ph0-ph2 so the end-of-tile vmcnt(0) covers loads issued >=1.5k cy earlier.
// Raw s_barrier between phases (waves stay loosely phase-locked -> LDS/MFMA pipelining),
// setprio(1) around each 16-MFMA cluster. chunk^(row&7) both-sides swizzle (0 conflicts
// measured R3/R4). Bijective XCD swizzle (grid.x % 8 == 0 for all calls).
// MODE 0: f32 C out, no bias. MODE 1: bf16 QKV out + bias; V col-blocks (bn>=8) are
// written TRANSPOSED to vt[b][e][t] instead (kills the transpose kernel).
template <int MODE>
__global__ __launch_bounds__(512, 2) void gemm_kernel(
    const __bf16* __restrict__ A, int lda,
    const __bf16* __restrict__ B, int ldb, long long bBatchStride, int bmShift,
    const float* __restrict__ bias,
    void* __restrict__ C, int ldc,
    __bf16* __restrict__ vt,
    int nTiles, int nt,
    int khA, int khB, long long khCBytes) {
  constexpr int ABYTES = 256 * 128;          // 32 KiB
  constexpr int BUFB = ABYTES + 256 * 128;   // 64 KiB
  __shared__ __attribute__((aligned(128))) char lds[2 * BUFB];

  const int tid = threadIdx.x;
  const int lane = tid & 63;
  const int wid = tid >> 6;
  const int wm = wid >> 2, wn = wid & 3;  // 2M x 4N waves; wave tile 128x64
  const int lo = lane & 15, hi = lane >> 4;

  // bijective XCD swizzle (gridDim.x % 8 == 0)
  const int cpx = gridDim.x >> 3;
  const int bid = blockIdx.x;
  const int swz = (bid & 7) * cpx + (bid >> 3);
  const int bm = swz / nTiles, bn = swz % nTiles;
  const int kh = blockIdx.y;

  const __bf16* Ab = A + kh * khA;
  const __bf16* Bb = B + (long long)(bm >> bmShift) * bBatchStride + kh * khB;

  // staging: slot s -> LDS row r=s>>3, chunk=s&7; global source chunk inverse-swizzled
  const __bf16* gA[4]; int lA[4];
  const __bf16* gB[4]; int lB[4];
#pragma unroll
  for (int l = 0; l < 4; ++l) {
    int s = l * 512 + tid, r = s >> 3;
    int c = (s & 7) ^ (r & 7);
    gA[l] = Ab + (long long)(bm * 256 + r) * lda + c * 8;
    lA[l] = s * 16;
    gB[l] = Bb + (long long)(bn * 256 + r) * ldb + c * 8;
    lB[l] = ABYTES + s * 16;
  }

  const int cx = ((hi ^ (lo & 7)) << 4);
  const int aR = wm * 128 + lo;        // + mi*16, row in A region
  const int bR = wn * 64 + lo;         // + ni*16, row in B region

  f32x4 acc[8][4] = {};
  bf16x8 bv[4][2];

#define STAGE_ALL(tt, buf)                                           \
  do {                                                               \
    const long long ko_ = (long long)(tt) * 64;                      \
    char* lb_ = lds + (buf) * BUFB;                                  \
    _Pragma("unroll") for (int l = 0; l < 4; ++l) {                  \
      gload_lds16(gA[l] + ko_, lb_ + lA[l]);                         \
      gload_lds16(gB[l] + ko_, lb_ + lB[l]);                         \
    }                                                                \
  } while (0)

#define PHASE(mi0, STG)                                                              \
  {                                                                                  \
    bf16x8 a00 = *(const bf16x8*)(base + (aR + (mi0) * 16) * 128 + cx);              \
    bf16x8 a01 = *(const bf16x8*)(base + (aR + (mi0) * 16) * 128 + (cx ^ 64));       \
    bf16x8 a10 = *(const bf16x8*)(base + (aR + (mi0) * 16 + 16) * 128 + cx);         \
    bf16x8 a11 = *(const bf16x8*)(base + (aR + (mi0) * 16 + 16) * 128 + (cx ^ 64));  \
    STG;                                                                             \
    __builtin_amdgcn_s_setprio(1);                                                   \
    _Pragma("unroll") for (int ni = 0; ni < 4; ++ni) {                               \
      acc[(mi0)][ni] = MFMA16x16(a00, bv[ni][0], acc[(mi0)][ni]);                    \
      acc[(mi0) + 1][ni] = MFMA16x16(a10, bv[ni][0], acc[(mi0) + 1][ni]);            \
    }                                                                                \
    _Pragma("unroll") for (int ni = 0; ni < 4; ++ni) {                               \
      acc[(mi0)][ni] = MFMA16x16(a01, bv[ni][1], acc[(mi0)][ni]);                    \
      acc[(mi0) + 1][ni] = MFMA16x16(a11, bv[ni][1], acc[(mi0) + 1][ni]);            \
    }                                                                                \
    __builtin_amdgcn_s_setprio(0);                                                   \
  }

  // prologue
  STAGE_ALL(0, 0);
  WAITV(0);
  __builtin_amdgcn_s_barrier();
  __builtin_amdgcn_sched_barrier(0);

  for (int t = 0; t < nt; ++t) {
    const char* base = lds + (t & 1) * BUFB;
    char* sb = lds + ((t + 1) & 1) * BUFB;
    const long long ko = (long long)(t + 1) * 64;
    const bool st = (t + 1 < nt);

    // ph0: read all B frags + A mi{0,1}; stage 3
#pragma unroll
    for (int ni = 0; ni < 4; ++ni) {
      bv[ni][0] = *(const bf16x8*)(base + (bR + ni * 16) * 128 + ABYTES + cx);
      bv[ni][1] = *(const bf16x8*)(base + (bR + ni * 16) * 128 + ABYTES + (cx ^ 64));
    }
    PHASE(0, if (st) {
      gload_lds16(gA[0] + ko, sb + lA[0]);
      gload_lds16(gA[1] + ko, sb + lA[1]);
      gload_lds16(gA[2] + ko, sb + lA[2]);
    });
    __builtin_amdgcn_s_barrier();
    // ph1
    PHASE(2, if (st) {
      gload_lds16(gA[3] + ko, sb + lA[3]);
      gload_lds16(gB[0] + ko, sb + lB[0]);
      gload_lds16(gB[1] + ko, sb + lB[1]);
    });
    __builtin_amdgcn_s_barrier();
    // ph2
    PHASE(4, if (st) {
      gload_lds16(gB[2] + ko, sb + lB[2]);
      gload_lds16(gB[3] + ko, sb + lB[3]);
    });
    __builtin_amdgcn_s_barrier();
    // ph3
    PHASE(6, );

    if (st) {
      WAITV(0);  // t+1's 8 loads were issued >=1.5k cy ago -> near-free
      __builtin_amdgcn_s_barrier();
      __builtin_amdgcn_sched_barrier(0);
    }
  }
#undef STAGE_ALL
#undef PHASE

  // epilogue: C/D map col=lane&15, row=(lane>>4)*4+j  [m89-verified]
  char* Cb = (char*)C + kh * khCBytes;
  const long long row0 = (long long)bm * 256 + wm * 128 + hi * 4;
  const long long col0 = (long long)bn * 256 + wn * 64 + lo;

  if (MODE == 0) {
#pragma unroll
    for (int ni = 0; ni < 4; ++ni) {
      const long long col = col0 + ni * 16;
#pragma unroll
      for (int mi = 0; mi < 8; ++mi) {
#pragma unroll
        for (int j = 0; j < 4; ++j)
          ((float*)Cb)[(row0 + mi * 16 + j) * ldc + col] = acc[mi][ni][j];
      }
    }
  } else {
    if (bn < 8) {
      // Q/K block: bf16 row-major into QKV
#pragma unroll
      for (int ni = 0; ni < 4; ++ni) {
        const long long col = col0 + ni * 16;
        const float bvs = bias[col];
#pragma unroll
        for (int mi = 0; mi < 8; ++mi) {
#pragma unroll
          for (int j = 0; j < 4; ++j)
            ((__bf16*)Cb)[(row0 + mi * 16 + j) * ldc + col] = (__bf16)(acc[mi][ni][j] + bvs);
        }
      }
    } else {
      // V block: write transposed into vt[b][e][t], bf16x4 along t
      const int b = bm >> 3;
      __bf16* vtb = vt + (long long)b * 2097152;
      const int trow = (bm & 7) * 256 + wm * 128 + hi * 4;
#pragma unroll
      for (int ni = 0; ni < 4; ++ni) {
        const long long e = (long long)(bn - 8) * 256 + wn * 64 + ni * 16 + lo;
        const float bvs = bias[2048 + e];
#pragma unroll
        for (int mi = 0; mi < 8; ++mi) {
          bf16x4 o;
#pragma unroll
          for (int j = 0; j < 4; ++j) o[j] = (__bf16)(acc[mi][ni][j] + bvs);
          *(bf16x4*)(vtb + e * 2048 + trow + mi * 16) = o;
        }
      }
    }
  }
}

// ---------------- row softmax in place: f32 row[2048] -> bf16 row (first half) ----------------
__global__ __launch_bounds__(256) void softmax_kernel(float* __restrict__ S) {
  const long long row = blockIdx.x;
  float* p = S + row * 2048;
  const int tid = threadIdx.x;
  const int lane = tid & 63, wid = tid >> 6;
  f32x4 v0 = *(const f32x4*)(p + tid * 8);
  f32x4 v1 = *(const f32x4*)(p + tid * 8 + 4);
  float xv[8] = {v0[0], v0[1], v0[2], v0[3], v1[0], v1[1], v1[2], v1[3]};
  float mx = xv[0];
#pragma unroll
  for (int j = 1; j < 8; ++j) mx = fmaxf(mx, xv[j]);
#pragma unroll
  for (int off = 32; off >= 1; off >>= 1) mx = fmaxf(mx, __shfl_xor(mx, off));
  __shared__ float red[8];
  if (lane == 0) red[wid] = mx;
  __syncthreads();
  mx = fmaxf(fmaxf(red[0], red[1]), fmaxf(red[2], red[3]));
  float e[8];
  float sum = 0.f;
#pragma unroll
  for (int j = 0; j < 8; ++j) {
    e[j] = __expf(xv[j] - mx);
    sum += e[j];
  }
#pragma unroll
  for (int off = 32; off >= 1; off >>= 1) sum += __shfl_xor(sum, off);
  if (lane == 0) red[4 + wid] = sum;
  __syncthreads();
  sum = red[4] + red[5] + red[6] + red[7];
  const float inv = 1.0f / sum;
  bf16x8 ov;
#pragma unroll
  for (int j = 0; j < 8; ++j) ov[j] = (__bf16)(e[j] * inv);
  *(bf16x8*)((__bf16*)p + tid * 8) = ov;
}

// ---------------- add split-K partials: out = p0 + p1 ----------------
__global__ __launch_bounds__(256) void add_kernel(const float* __restrict__ p0,
                                                  const float* __restrict__ p1,
                                                  float* __restrict__ o, long n) {
  long i = ((long)blockIdx.x * 256 + threadIdx.x) * 4;
  const long stride = (long)gridDim.x * 256 * 4;
  for (; i < n; i += stride) {
    f32x4 a = *(const f32x4*)(p0 + i);
    f32x4 b = *(const f32x4*)(p1 + i);
    *(f32x4*)(o + i) = a + b;
  }
}

extern "C" void kernel_launch(void* const* d_in, const int* in_sizes, int n_in,
                              void* d_out, int out_size, void* d_ws, size_t ws_size,
                              hipStream_t stream) {
  (void)in_sizes; (void)n_in; (void)out_size;
  const float* x  = (const float*)d_in[0];
  const float* Wq = (const float*)d_in[1];
  const float* bq = (const float*)d_in[2];
  const float* Wk = (const float*)d_in[3];
  const float* bk = (const float*)d_in[4];
  const float* Wv = (const float*)d_in[5];
  const float* bv = (const float*)d_in[6];
  float* out = (float*)d_out;
  char* ws = (char*)d_ws;
  if (ws_size < 157298688ULL) return;

  __bf16* x16  = (__bf16*)(ws + 0);          // 8192*1024*2      = 16,777,216
  __bf16* Wt   = (__bf16*)(ws + 16777216);   // 3072*1024*2      =  6,291,456
  float*  bqkv = (float*)(ws + 23068672);    // 3072*4           =     12,288
  __bf16* QKV  = (__bf16*)(ws + 23080960);   // 8192*3072*2      = 50,331,648
  __bf16* Vt   = (__bf16*)(ws + 73412608);   // 4*1024*2048*2    = 16,777,216
  float*  S    = (float*)(ws + 90189824);    // 4*2048*2048*4    = 67,108,864
  // split-K partials reuse dead regions (x16/Wt/QKV are unused by GEMM3 time):
  float*  P0   = (float*)(ws + 0);           // 8192*1024*4      = 33,554,432
  float*  P1   = (float*)(ws + 33554432);    // 8192*1024*4      = 33,554,432

  pack_x_kernel<<<2048, 256, 0, stream>>>(x, x16, 8388608L);
  pack_w_kernel<<<dim3(16, 16, 3), 256, 0, stream>>>(Wq, Wk, Wv, Wt);
  pack_bias_kernel<<<12, 256, 0, stream>>>(bq, bk, bv, bqkv);

  // GEMM1: QKV[8192,3072] = x16 @ Wt^T + bias; Q/K bf16 row-major, V written into Vt
  // transposed. grid 32x12 = 384.
  gemm_kernel<1><<<dim3(384, 1), 512, 0, stream>>>(
      x16, 1024, Wt, 1024, 0LL, 30, bqkv, QKV, 3072, Vt, 12, 16, 0, 0, 0LL);

  // GEMM2: S[8192,2048] = Q @ K^T (f32); grid 32x8 = 256 = 1 full round
  gemm_kernel<0><<<dim3(256, 1), 512, 0, stream>>>(
      QKV, 3072, QKV + 1024, 3072, 6291456LL, 3, nullptr, S, 2048, nullptr, 8, 16, 0, 0, 0LL);

  // softmax rows of S, write bf16 P in place
  softmax_kernel<<<8192, 256, 0, stream>>>(S);

  // GEMM3: out = P @ Vt^T, split-K=2 (blockIdx.y = kh); grid 128x2 -> 256 blocks
  gemm_kernel<0><<<dim3(128, 2), 512, 0, stream>>>(
      (const __bf16*)S, 4096, Vt, 2048, 2097152LL, 3, nullptr, P0, 1024, nullptr,
      4, 16, 1024, 1024, 33554432LL);

  add_kernel<<<2048, 256, 0, stream>>>(P0, P1, out, 8388608L);
}